// Round 1
// baseline (483.546 us; speedup 1.0000x reference)
//
#include <hip/hip_runtime.h>
#include <cstdint>

// Problem constants (from reference): B=8192, DIN=DOUT=4096, NC=64
#define BB   8192
#define DIN  4096
#define DOUT 4096
#define NCL  64

typedef __bf16 bf16;
typedef __attribute__((ext_vector_type(8))) __bf16 bf16x8;
typedef __attribute__((ext_vector_type(4))) float   f32x4;

// CK-proven addrspace cast pattern for global_load_lds
#define GAS(p) (reinterpret_cast<uint32_t __attribute__((address_space(1)))*>(reinterpret_cast<uintptr_t>(p)))
#define LAS(p) (reinterpret_cast<uint32_t __attribute__((address_space(3)))*>(reinterpret_cast<uintptr_t>(p)))

// ---------------------------------------------------------------------------
// Kernel 1: prologue. Per 128x128 tile:
//   tmpL = cluster @ style_L, tmpR = cluster @ style_R  (K = NC = 64, MFMA)
//   A' = bf16(x * tmpL)  and  tmpR (bf16) written to workspace.
// LDS layout (bf16, 128B rows = 8 chunks of 16B), chunk swizzled ^(row&7):
//   CL  [128 b-rows][64 c]   @ 0      (A operand)
//   SL  [128 cols][64 c]     @ 16384  (B^T operand for style_L)
//   SR  [128 cols][64 c]     @ 32768  (B^T operand for style_R)
// ---------------------------------------------------------------------------
__global__ __launch_bounds__(256) void prologue_kernel(
    const float* __restrict__ x, const float* __restrict__ cl,
    const float* __restrict__ sL, const float* __restrict__ sR,
    bf16* __restrict__ Ap, bf16* __restrict__ tR)
{
    __shared__ uint4 lds_u4[3072]; // 48 KiB
    char* lds = (char*)lds_u4;
    const int t    = threadIdx.x;
    const int lane = t & 63;
    const int w    = t >> 6;
    const int wm   = w >> 1, wn = w & 1;
    const int r0   = blockIdx.x * 128;  // b rows
    const int c0   = blockIdx.y * 128;  // columns (shared DIN/DOUT = 4096)

    // --- stage cluster tile (128x64 f32 -> bf16), coalesced reads
    #pragma unroll
    for (int i = 0; i < 4; i++) {
        int tk  = t + i * 256;
        int row = tk >> 3, ch = tk & 7;
        const float* src = cl + (size_t)(r0 + row) * NCL + ch * 8;
        float4 v0 = *(const float4*)src;
        float4 v1 = *(const float4*)(src + 4);
        bf16x8 pk;
        pk[0]=(bf16)v0.x; pk[1]=(bf16)v0.y; pk[2]=(bf16)v0.z; pk[3]=(bf16)v0.w;
        pk[4]=(bf16)v1.x; pk[5]=(bf16)v1.y; pk[6]=(bf16)v1.z; pk[7]=(bf16)v1.w;
        *(bf16x8*)(lds + row * 128 + ((ch ^ (row & 7)) << 4)) = pk;
    }
    // --- stage style tiles transposed: SL[n][k] = style_L[k][c0+n]
    //     (fixed (c,j): lanes read consecutive n -> coalesced)
    #pragma unroll
    for (int i = 0; i < 4; i++) {
        int tk = t + i * 256;
        int n  = tk & 127, c = tk >> 7;
        bf16x8 pl, pr;
        #pragma unroll
        for (int j = 0; j < 8; j++) {
            pl[j] = (bf16)sL[(size_t)(c * 8 + j) * DIN  + c0 + n];
            pr[j] = (bf16)sR[(size_t)(c * 8 + j) * DOUT + c0 + n];
        }
        int off = n * 128 + ((c ^ (n & 7)) << 4);
        *(bf16x8*)(lds + 16384 + off) = pl;
        *(bf16x8*)(lds + 32768 + off) = pr;
    }
    __syncthreads();

    f32x4 accL[4][4] = {};
    f32x4 accR[4][4] = {};
    #pragma unroll
    for (int s = 0; s < 2; s++) {           // two K=32 steps cover NC=64
        bf16x8 a[4], bl[4], br[4];
        #pragma unroll
        for (int m = 0; m < 4; m++) {
            int row = wm * 64 + m * 16 + (lane & 15);
            int ch  = s * 4 + (lane >> 4);
            a[m] = *(bf16x8*)(lds + row * 128 + ((ch ^ (row & 7)) << 4));
        }
        #pragma unroll
        for (int n = 0; n < 4; n++) {
            int row = wn * 64 + n * 16 + (lane & 15);
            int ch  = s * 4 + (lane >> 4);
            int off = row * 128 + ((ch ^ (row & 7)) << 4);
            bl[n] = *(bf16x8*)(lds + 16384 + off);
            br[n] = *(bf16x8*)(lds + 32768 + off);
        }
        #pragma unroll
        for (int m = 0; m < 4; m++)
            #pragma unroll
            for (int n = 0; n < 4; n++) {
                accL[m][n] = __builtin_amdgcn_mfma_f32_16x16x32_bf16(a[m], bl[n], accL[m][n], 0, 0, 0);
                accR[m][n] = __builtin_amdgcn_mfma_f32_16x16x32_bf16(a[m], br[n], accR[m][n], 0, 0, 0);
            }
    }

    // epilogue: A' = bf16(x * tmpL), tR = bf16(tmpR)
    // C/D layout: col = lane&15, row = (lane>>4)*4 + j   [m89/m91 verified]
    #pragma unroll
    for (int m = 0; m < 4; m++) {
        int rbase = r0 + wm * 64 + m * 16 + ((lane >> 4) << 2);
        #pragma unroll
        for (int n = 0; n < 4; n++) {
            int col = c0 + wn * 64 + n * 16 + (lane & 15);
            #pragma unroll
            for (int j = 0; j < 4; j++) {
                size_t idx = (size_t)(rbase + j) * DIN + col; // DIN==DOUT
                Ap[idx] = (bf16)(x[idx] * accL[m][n][j]);
                tR[idx] = (bf16)accR[m][n][j];
            }
        }
    }
}

// ---------------------------------------------------------------------------
// Kernel 2: W (DIN x DOUT, f32) -> Wt (DOUT x DIN, bf16)  [B^T layout for GEMM]
// Reads coalesced (lanes sweep n), each thread writes a 64B contiguous chunk.
// ---------------------------------------------------------------------------
__global__ __launch_bounds__(256) void transpose_kernel(
    const float* __restrict__ W, bf16* __restrict__ Wt)
{
    const int t  = threadIdx.x;
    const int n  = blockIdx.x * 256 + t;   // grid.x = 16
    const int k0 = blockIdx.y * 32;        // grid.y = 128
    bf16x8 v[4];
    #pragma unroll
    for (int q = 0; q < 4; q++)
        #pragma unroll
        for (int j = 0; j < 8; j++)
            v[q][j] = (bf16)W[(size_t)(k0 + q * 8 + j) * DOUT + n];
    bf16* dst = Wt + (size_t)n * DIN + k0;
    #pragma unroll
    for (int q = 0; q < 4; q++)
        *(bf16x8*)(dst + q * 8) = v[q];
}

// ---------------------------------------------------------------------------
// Kernel 3: main GEMM (m97 structure): out = (A' @ W) * tmpR
// 128x128 tile, BK=32, 4 waves (2x2), 4x4 16x16x32 fragments per wave.
// global_load_lds width=16 (linear LDS dest); global source pre-swizzled with
// slot = chunk ^ ((row>>1)&3) so frag ds_read_b128 is 2-way (free).
// LDS: As @0 (8KB), Bs @8192 (8KB). Rows are 64B = 4 chunks of 16B.
// ---------------------------------------------------------------------------
__global__ __launch_bounds__(256) void gemm_kernel(
    const bf16* __restrict__ Ap, const bf16* __restrict__ Wt,
    const bf16* __restrict__ tR, float* __restrict__ out)
{
    __shared__ uint4 lds_u4[1024]; // 16 KiB
    char* lds = (char*)lds_u4;
    const int t    = threadIdx.x;
    const int lane = t & 63;
    const int w    = t >> 6;
    const int wm   = w >> 1, wn = w & 1;

    // XCD-aware swizzle (2048 blocks % 8 == 0 -> simple form is bijective),
    // then group-of-8 m-tiles for L2 locality within each XCD chunk.
    int bid = blockIdx.x;                  // 0..2047
    int s   = (bid & 7) * 256 + (bid >> 3);
    int mt  = (s >> 8) * 8 + (s & 7);      // 0..63
    int nt  = (s >> 3) & 31;               // 0..31
    const size_t brow = (size_t)mt * 128;
    const size_t bcol = (size_t)nt * 128;

    // staging: thread t covers row = i*64 + (t>>2), 16B slot = t&3
    const int srow = t >> 2;
    const int slot = t & 3;
    const int gch  = slot ^ ((srow >> 1) & 3);   // (row+64) gives same value
    const bf16* srcA = Ap + (brow + srow) * DIN + gch * 8;
    const bf16* srcB = Wt + (bcol + srow) * DIN + gch * 8;

    // loop-invariant fragment LDS byte offsets
    int aoff[4], boff[4];
    #pragma unroll
    for (int m = 0; m < 4; m++) {
        int row = wm * 64 + m * 16 + (lane & 15);
        aoff[m] = row * 64 + (((lane >> 4) ^ ((row >> 1) & 3)) << 4);
    }
    #pragma unroll
    for (int n = 0; n < 4; n++) {
        int row = wn * 64 + n * 16 + (lane & 15);
        boff[n] = 8192 + row * 64 + (((lane >> 4) ^ ((row >> 1) & 3)) << 4);
    }

    f32x4 acc[4][4] = {};
    for (int kt = 0; kt < DIN / 32; kt++) {
        const bf16* a = srcA + kt * 32;
        const bf16* b = srcB + kt * 32;
        __builtin_amdgcn_global_load_lds(GAS(a),            LAS(lds + t * 16),         16, 0, 0);
        __builtin_amdgcn_global_load_lds(GAS(a + 64 * DIN), LAS(lds + 4096 + t * 16),  16, 0, 0);
        __builtin_amdgcn_global_load_lds(GAS(b),            LAS(lds + 8192 + t * 16),  16, 0, 0);
        __builtin_amdgcn_global_load_lds(GAS(b + 64 * DIN), LAS(lds + 12288 + t * 16), 16, 0, 0);
        __syncthreads();   // compiler drains vmcnt(0) here -> LDS data ready

        bf16x8 af[4], bfr[4];
        #pragma unroll
        for (int m = 0; m < 4; m++) af[m]  = *(const bf16x8*)(lds + aoff[m]);
        #pragma unroll
        for (int n = 0; n < 4; n++) bfr[n] = *(const bf16x8*)(lds + boff[n]);
        #pragma unroll
        for (int m = 0; m < 4; m++)
            #pragma unroll
            for (int n = 0; n < 4; n++)
                acc[m][n] = __builtin_amdgcn_mfma_f32_16x16x32_bf16(af[m], bfr[n], acc[m][n], 0, 0, 0);
        __syncthreads();   // all waves done reading before next-tile staging
    }

    // epilogue: out = acc * tmpR (f32 write)
    #pragma unroll
    for (int m = 0; m < 4; m++) {
        size_t rbase = brow + wm * 64 + m * 16 + ((lane >> 4) << 2);
        #pragma unroll
        for (int n = 0; n < 4; n++) {
            size_t col = bcol + wn * 64 + n * 16 + (lane & 15);
            #pragma unroll
            for (int j = 0; j < 4; j++) {
                size_t idx = (rbase + j) * DOUT + col;
                out[idx] = acc[m][n][j] * (float)tR[idx];
            }
        }
    }
}

// ---------------------------------------------------------------------------
extern "C" void kernel_launch(void* const* d_in, const int* in_sizes, int n_in,
                              void* d_out, int out_size, void* d_ws, size_t ws_size,
                              hipStream_t stream)
{
    (void)in_sizes; (void)n_in; (void)out_size;
    const float* x  = (const float*)d_in[0];
    const float* cl = (const float*)d_in[1];
    const float* W  = (const float*)d_in[2];
    const float* sL = (const float*)d_in[3];
    const float* sR = (const float*)d_in[4];
    float* out = (float*)d_out;

    // workspace layout: A' (64MiB) | Wt (32MiB) | tmpR (64MiB)  = 160MiB
    const size_t AP_BYTES = (size_t)BB * DIN * sizeof(bf16);
    const size_t WT_BYTES = (size_t)DIN * DOUT * sizeof(bf16);
    const size_t TR_BYTES = (size_t)BB * DOUT * sizeof(bf16);
    if (ws_size < AP_BYTES + WT_BYTES + TR_BYTES) return; // would corrupt; bail loudly

    char* ws = (char*)d_ws;
    bf16* Ap = (bf16*)ws;
    bf16* Wt = (bf16*)(ws + AP_BYTES);
    bf16* tR = (bf16*)(ws + AP_BYTES + WT_BYTES);

    prologue_kernel<<<dim3(BB / 128, DIN / 128), 256, 0, stream>>>(x, cl, sL, sR, Ap, tR);
    transpose_kernel<<<dim3(DOUT / 256, DIN / 32), 256, 0, stream>>>(W, Wt);
    gemm_kernel<<<dim3((BB / 128) * (DOUT / 128)), 256, 0, stream>>>(Ap, Wt, tR, out);
}

// Round 2
// 383.531 us; speedup vs baseline: 1.2608x; 1.2608x over previous
//
#include <hip/hip_runtime.h>
#include <cstdint>

// Problem constants (from reference): B=8192, DIN=DOUT=4096, NC=64
#define BB   8192
#define DIN  4096
#define DOUT 4096
#define NCL  64

typedef __bf16 bf16;
typedef __attribute__((ext_vector_type(8))) __bf16 bf16x8;
typedef __attribute__((ext_vector_type(4))) float   f32x4;

// CK-proven addrspace cast pattern for global_load_lds
#define GAS(p) (reinterpret_cast<uint32_t __attribute__((address_space(1)))*>(reinterpret_cast<uintptr_t>(p)))
#define LAS(p) (reinterpret_cast<uint32_t __attribute__((address_space(3)))*>(reinterpret_cast<uintptr_t>(p)))

#define WAITV(n) asm volatile("s_waitcnt vmcnt(" #n ")" ::: "memory")
#define WAITL()  asm volatile("s_waitcnt lgkmcnt(0)" ::: "memory")
#define BARR()   __builtin_amdgcn_s_barrier()
#define SCHED0() __builtin_amdgcn_sched_barrier(0)

// ---------------------------------------------------------------------------
// Kernel 1: prologue (unchanged from round 1 — verified correct).
// tmpL = cluster@style_L, tmpR = cluster@style_R (K=NC=64 via MFMA);
// writes A' = bf16(x*tmpL) and tR = bf16(tmpR).
// ---------------------------------------------------------------------------
__global__ __launch_bounds__(256) void prologue_kernel(
    const float* __restrict__ x, const float* __restrict__ cl,
    const float* __restrict__ sL, const float* __restrict__ sR,
    bf16* __restrict__ Ap, bf16* __restrict__ tR)
{
    __shared__ uint4 lds_u4[3072]; // 48 KiB
    char* lds = (char*)lds_u4;
    const int t    = threadIdx.x;
    const int lane = t & 63;
    const int w    = t >> 6;
    const int wm   = w >> 1, wn = w & 1;
    const int r0   = blockIdx.x * 128;
    const int c0   = blockIdx.y * 128;

    #pragma unroll
    for (int i = 0; i < 4; i++) {
        int tk  = t + i * 256;
        int row = tk >> 3, ch = tk & 7;
        const float* src = cl + (size_t)(r0 + row) * NCL + ch * 8;
        float4 v0 = *(const float4*)src;
        float4 v1 = *(const float4*)(src + 4);
        bf16x8 pk;
        pk[0]=(bf16)v0.x; pk[1]=(bf16)v0.y; pk[2]=(bf16)v0.z; pk[3]=(bf16)v0.w;
        pk[4]=(bf16)v1.x; pk[5]=(bf16)v1.y; pk[6]=(bf16)v1.z; pk[7]=(bf16)v1.w;
        *(bf16x8*)(lds + row * 128 + ((ch ^ (row & 7)) << 4)) = pk;
    }
    #pragma unroll
    for (int i = 0; i < 4; i++) {
        int tk = t + i * 256;
        int n  = tk & 127, c = tk >> 7;
        bf16x8 pl, pr;
        #pragma unroll
        for (int j = 0; j < 8; j++) {
            pl[j] = (bf16)sL[(size_t)(c * 8 + j) * DIN  + c0 + n];
            pr[j] = (bf16)sR[(size_t)(c * 8 + j) * DOUT + c0 + n];
        }
        int off = n * 128 + ((c ^ (n & 7)) << 4);
        *(bf16x8*)(lds + 16384 + off) = pl;
        *(bf16x8*)(lds + 32768 + off) = pr;
    }
    __syncthreads();

    f32x4 accL[4][4] = {};
    f32x4 accR[4][4] = {};
    #pragma unroll
    for (int s = 0; s < 2; s++) {
        bf16x8 a[4], bl[4], br[4];
        #pragma unroll
        for (int m = 0; m < 4; m++) {
            int row = wm * 64 + m * 16 + (lane & 15);
            int ch  = s * 4 + (lane >> 4);
            a[m] = *(bf16x8*)(lds + row * 128 + ((ch ^ (row & 7)) << 4));
        }
        #pragma unroll
        for (int n = 0; n < 4; n++) {
            int row = wn * 64 + n * 16 + (lane & 15);
            int ch  = s * 4 + (lane >> 4);
            int off = row * 128 + ((ch ^ (row & 7)) << 4);
            bl[n] = *(bf16x8*)(lds + 16384 + off);
            br[n] = *(bf16x8*)(lds + 32768 + off);
        }
        #pragma unroll
        for (int m = 0; m < 4; m++)
            #pragma unroll
            for (int n = 0; n < 4; n++) {
                accL[m][n] = __builtin_amdgcn_mfma_f32_16x16x32_bf16(a[m], bl[n], accL[m][n], 0, 0, 0);
                accR[m][n] = __builtin_amdgcn_mfma_f32_16x16x32_bf16(a[m], br[n], accR[m][n], 0, 0, 0);
            }
    }

    #pragma unroll
    for (int m = 0; m < 4; m++) {
        int rbase = r0 + wm * 64 + m * 16 + ((lane >> 4) << 2);
        #pragma unroll
        for (int n = 0; n < 4; n++) {
            int col = c0 + wn * 64 + n * 16 + (lane & 15);
            #pragma unroll
            for (int j = 0; j < 4; j++) {
                size_t idx = (size_t)(rbase + j) * DIN + col;
                Ap[idx] = (bf16)(x[idx] * accL[m][n][j]);
                tR[idx] = (bf16)accR[m][n][j];
            }
        }
    }
}

// ---------------------------------------------------------------------------
// Kernel 2: W (DIN x DOUT f32) -> Wt (DOUT x DIN bf16)  (unchanged)
// ---------------------------------------------------------------------------
__global__ __launch_bounds__(256) void transpose_kernel(
    const float* __restrict__ W, bf16* __restrict__ Wt)
{
    const int t  = threadIdx.x;
    const int n  = blockIdx.x * 256 + t;
    const int k0 = blockIdx.y * 32;
    bf16x8 v[4];
    #pragma unroll
    for (int q = 0; q < 4; q++)
        #pragma unroll
        for (int j = 0; j < 8; j++)
            v[q][j] = (bf16)W[(size_t)(k0 + q * 8 + j) * DOUT + n];
    bf16* dst = Wt + (size_t)n * DIN + k0;
    #pragma unroll
    for (int q = 0; q < 4; q++)
        *(bf16x8*)(dst + q * 8) = v[q];
}

// ---------------------------------------------------------------------------
// Kernel 3: 256x256-tile 8-phase GEMM (T2+T3+T4+T5): out = (A' @ W) * tmpR
//
// 512 threads = 8 waves (2M x 4N). BK=64. LDS 128 KiB:
//   buf{0,1} x { Ah0@0, Ah1@16K, Bh0@32K, Bh1@48K } (16 KiB half-tiles).
// Swizzle: 16B-chunk slot = chunk ^ (row&7) (0-conflict measured in r1);
// global_load_lds dest linear, source chunk pre-inverse-swizzled.
// Per K-tile t (4 phases), computing from buf[t&1]:
//   P1: ds_read A-quad0 + all B; stage (t+1).Ah1 -> buf[t&1 ^ 1];
//       bar; lgkm(0); MFMA(q00); bar      (all reads complete before bar2!)
//   P2: stage (t+2).Bh0 -> buf[t&1] (B slots dead since P1); bar; MFMA(q01); bar
//   P3: ds_read A-quad1; stage (t+2).Bh1; bar; lgkm(0); MFMA(q11); bar
//   P4: stage (t+2).Ah0 (A slots dead since P3); bar; MFMA(q10);
//       vmcnt(6)  <- tile t+1 fully landed, t+2's 3 half-tiles in flight; bar
// Counted vmcnt: every thread issues exactly 2 loads/phase -> uniform counts.
// ---------------------------------------------------------------------------
template<int CUR>
__device__ __forceinline__ void tile_step(char* lds, int tid,
    const bf16* pA1, const bf16* pA2, const bf16* pB1, const bf16* pB2,
    int k1, int k2,
    int aoff0, int aoff1, int boff0, int boff1,
    bf16x8 a[4][2], bf16x8 b[4][2], f32x4 acc[8][4])
{
    constexpr int CB = CUR * 65536;        // current buffer base
    constexpr int OB = (CUR ^ 1) * 65536;  // other buffer base
    constexpr int HALF = 128 * DIN;        // element offset of half 1

    // ---- P1
    #pragma unroll
    for (int mq = 0; mq < 4; ++mq) {
        a[mq][0] = *(const bf16x8*)(lds + CB + mq * 2048 + aoff0);
        a[mq][1] = *(const bf16x8*)(lds + CB + mq * 2048 + aoff1);
    }
    #pragma unroll
    for (int nb = 0; nb < 4; ++nb) {
        b[nb][0] = *(const bf16x8*)(lds + CB + nb * 2048 + boff0);
        b[nb][1] = *(const bf16x8*)(lds + CB + nb * 2048 + boff1);
    }
    __builtin_amdgcn_global_load_lds(GAS(pA1 + HALF + k1), LAS(lds + OB + 16384 + tid * 16), 16, 0, 0);
    __builtin_amdgcn_global_load_lds(GAS(pA2 + HALF + k1), LAS(lds + OB + 16384 + 8192 + tid * 16), 16, 0, 0);
    BARR();
    WAITL(); SCHED0();
    __builtin_amdgcn_s_setprio(1);
    #pragma unroll
    for (int mq = 0; mq < 4; ++mq)
        #pragma unroll
        for (int nq = 0; nq < 2; ++nq) {
            acc[mq][nq] = __builtin_amdgcn_mfma_f32_16x16x32_bf16(a[mq][0], b[nq][0], acc[mq][nq], 0, 0, 0);
            acc[mq][nq] = __builtin_amdgcn_mfma_f32_16x16x32_bf16(a[mq][1], b[nq][1], acc[mq][nq], 0, 0, 0);
        }
    __builtin_amdgcn_s_setprio(0);
    BARR();

    // ---- P2
    __builtin_amdgcn_global_load_lds(GAS(pB1 + k2), LAS(lds + CB + 32768 + tid * 16), 16, 0, 0);
    __builtin_amdgcn_global_load_lds(GAS(pB2 + k2), LAS(lds + CB + 32768 + 8192 + tid * 16), 16, 0, 0);
    BARR();
    __builtin_amdgcn_s_setprio(1);
    #pragma unroll
    for (int mq = 0; mq < 4; ++mq)
        #pragma unroll
        for (int nq = 0; nq < 2; ++nq) {
            acc[mq][2 + nq] = __builtin_amdgcn_mfma_f32_16x16x32_bf16(a[mq][0], b[2 + nq][0], acc[mq][2 + nq], 0, 0, 0);
            acc[mq][2 + nq] = __builtin_amdgcn_mfma_f32_16x16x32_bf16(a[mq][1], b[2 + nq][1], acc[mq][2 + nq], 0, 0, 0);
        }
    __builtin_amdgcn_s_setprio(0);
    BARR();

    // ---- P3
    #pragma unroll
    for (int mq = 0; mq < 4; ++mq) {
        a[mq][0] = *(const bf16x8*)(lds + CB + 8192 + mq * 2048 + aoff0);
        a[mq][1] = *(const bf16x8*)(lds + CB + 8192 + mq * 2048 + aoff1);
    }
    __builtin_amdgcn_global_load_lds(GAS(pB1 + HALF + k2), LAS(lds + CB + 49152 + tid * 16), 16, 0, 0);
    __builtin_amdgcn_global_load_lds(GAS(pB2 + HALF + k2), LAS(lds + CB + 49152 + 8192 + tid * 16), 16, 0, 0);
    BARR();
    WAITL(); SCHED0();
    __builtin_amdgcn_s_setprio(1);
    #pragma unroll
    for (int mq = 0; mq < 4; ++mq)
        #pragma unroll
        for (int nq = 0; nq < 2; ++nq) {
            acc[4 + mq][2 + nq] = __builtin_amdgcn_mfma_f32_16x16x32_bf16(a[mq][0], b[2 + nq][0], acc[4 + mq][2 + nq], 0, 0, 0);
            acc[4 + mq][2 + nq] = __builtin_amdgcn_mfma_f32_16x16x32_bf16(a[mq][1], b[2 + nq][1], acc[4 + mq][2 + nq], 0, 0, 0);
        }
    __builtin_amdgcn_s_setprio(0);
    BARR();

    // ---- P4
    __builtin_amdgcn_global_load_lds(GAS(pA1 + k2), LAS(lds + CB + tid * 16), 16, 0, 0);
    __builtin_amdgcn_global_load_lds(GAS(pA2 + k2), LAS(lds + CB + 8192 + tid * 16), 16, 0, 0);
    BARR();
    __builtin_amdgcn_s_setprio(1);
    #pragma unroll
    for (int mq = 0; mq < 4; ++mq)
        #pragma unroll
        for (int nq = 0; nq < 2; ++nq) {
            acc[4 + mq][nq] = __builtin_amdgcn_mfma_f32_16x16x32_bf16(a[mq][0], b[nq][0], acc[4 + mq][nq], 0, 0, 0);
            acc[4 + mq][nq] = __builtin_amdgcn_mfma_f32_16x16x32_bf16(a[mq][1], b[nq][1], acc[4 + mq][nq], 0, 0, 0);
        }
    __builtin_amdgcn_s_setprio(0);
    WAITV(6);
    BARR();
}

__global__ __launch_bounds__(512, 2) void gemm_kernel(
    const bf16* __restrict__ Ap, const bf16* __restrict__ Wt,
    const bf16* __restrict__ tR, float* __restrict__ out)
{
    __shared__ uint4 smem[8192]; // 128 KiB
    char* lds = (char*)smem;
    const int tid  = threadIdx.x;
    const int lane = tid & 63;
    const int w    = tid >> 6;
    const int wm   = w >> 2;   // 0..1
    const int wn   = w & 3;    // 0..3
    const int L = lane & 15, H = lane >> 4;

    // XCD-bijective swizzle: 512 blocks, 8 XCDs, 64 tiles each (4 mt x 16 nt)
    const int bid = blockIdx.x;
    const int xc  = bid & 7, ii = bid >> 3;
    const int mt  = xc * 4 + (ii >> 4);
    const int nt  = ii & 15;
    const size_t brow = (size_t)mt * 256;
    const size_t bcol = (size_t)nt * 256;

    // staging addressing: dest linear (tid*16), source chunk inverse-swizzled
    const int r1  = tid >> 3;
    const int gch = (tid & 7) ^ (r1 & 7);
    const bf16* pA1 = Ap + (brow + r1) * (size_t)DIN + gch * 8;
    const bf16* pA2 = pA1 + (size_t)64 * DIN;
    const bf16* pB1 = Wt + (bcol + r1) * (size_t)DIN + gch * 8;
    const bf16* pB2 = pB1 + (size_t)64 * DIN;

    // fragment ds_read offsets (swizzled): chunk = kk*4+H, slot = chunk^(L&7)
    const int swz0 = (H ^ (L & 7)) << 4;
    const int swz1 = ((4 + H) ^ (L & 7)) << 4;
    const int aoff0 = wm * 16384 + L * 128 + swz0;
    const int aoff1 = wm * 16384 + L * 128 + swz1;
    const int boff0 = 32768 + (wn >> 1) * 16384 + (wn & 1) * 8192 + L * 128 + swz0;
    const int boff1 = 32768 + (wn >> 1) * 16384 + (wn & 1) * 8192 + L * 128 + swz1;

    bf16x8 a[4][2], b[4][2];
    f32x4 acc[8][4] = {};

    // prologue: tile0 (4 half-tiles) -> buf0, tile1 (Bh0,Bh1,Ah0) -> buf1
    constexpr int HALF = 128 * DIN;
    __builtin_amdgcn_global_load_lds(GAS(pB1),            LAS(lds + 32768 + tid * 16), 16, 0, 0);
    __builtin_amdgcn_global_load_lds(GAS(pB2),            LAS(lds + 32768 + 8192 + tid * 16), 16, 0, 0);
    __builtin_amdgcn_global_load_lds(GAS(pB1 + HALF),     LAS(lds + 49152 + tid * 16), 16, 0, 0);
    __builtin_amdgcn_global_load_lds(GAS(pB2 + HALF),     LAS(lds + 49152 + 8192 + tid * 16), 16, 0, 0);
    __builtin_amdgcn_global_load_lds(GAS(pA1),            LAS(lds + tid * 16), 16, 0, 0);
    __builtin_amdgcn_global_load_lds(GAS(pA2),            LAS(lds + 8192 + tid * 16), 16, 0, 0);
    __builtin_amdgcn_global_load_lds(GAS(pA1 + HALF),     LAS(lds + 16384 + tid * 16), 16, 0, 0);
    __builtin_amdgcn_global_load_lds(GAS(pA2 + HALF),     LAS(lds + 16384 + 8192 + tid * 16), 16, 0, 0);
    __builtin_amdgcn_global_load_lds(GAS(pB1 + 64),       LAS(lds + 65536 + 32768 + tid * 16), 16, 0, 0);
    __builtin_amdgcn_global_load_lds(GAS(pB2 + 64),       LAS(lds + 65536 + 32768 + 8192 + tid * 16), 16, 0, 0);
    __builtin_amdgcn_global_load_lds(GAS(pB1 + HALF + 64),LAS(lds + 65536 + 49152 + tid * 16), 16, 0, 0);
    __builtin_amdgcn_global_load_lds(GAS(pB2 + HALF + 64),LAS(lds + 65536 + 49152 + 8192 + tid * 16), 16, 0, 0);
    __builtin_amdgcn_global_load_lds(GAS(pA1 + 64),       LAS(lds + 65536 + tid * 16), 16, 0, 0);
    __builtin_amdgcn_global_load_lds(GAS(pA2 + 64),       LAS(lds + 65536 + 8192 + tid * 16), 16, 0, 0);
    WAITV(6);
    BARR();

    #pragma unroll 1
    for (int t = 0; t < DIN / 64; t += 2) {
        tile_step<0>(lds, tid, pA1, pA2, pB1, pB2,
                     ((t + 1) & 63) * 64, ((t + 2) & 63) * 64,
                     aoff0, aoff1, boff0, boff1, a, b, acc);
        tile_step<1>(lds, tid, pA1, pA2, pB1, pB2,
                     ((t + 2) & 63) * 64, ((t + 3) & 63) * 64,
                     aoff0, aoff1, boff0, boff1, a, b, acc);
    }
    WAITV(0); // drain wrap-around junk prefetches

    // epilogue: out = acc * tmpR (f32)
    #pragma unroll
    for (int m = 0; m < 8; m++) {
        size_t rbase = brow + wm * 128 + m * 16 + (H << 2);
        #pragma unroll
        for (int n = 0; n < 4; n++) {
            size_t col = bcol + wn * 64 + n * 16 + L;
            #pragma unroll
            for (int j = 0; j < 4; j++) {
                size_t idx = (rbase + j) * DOUT + col;
                out[idx] = acc[m][n][j] * (float)tR[idx];
            }
        }
    }
}

// ---------------------------------------------------------------------------
extern "C" void kernel_launch(void* const* d_in, const int* in_sizes, int n_in,
                              void* d_out, int out_size, void* d_ws, size_t ws_size,
                              hipStream_t stream)
{
    (void)in_sizes; (void)n_in; (void)out_size;
    const float* x  = (const float*)d_in[0];
    const float* cl = (const float*)d_in[1];
    const float* W  = (const float*)d_in[2];
    const float* sL = (const float*)d_in[3];
    const float* sR = (const float*)d_in[4];
    float* out = (float*)d_out;

    const size_t AP_BYTES = (size_t)BB * DIN * sizeof(bf16);
    const size_t WT_BYTES = (size_t)DIN * DOUT * sizeof(bf16);
    const size_t TR_BYTES = (size_t)BB * DOUT * sizeof(bf16);
    if (ws_size < AP_BYTES + WT_BYTES + TR_BYTES) return;

    char* ws = (char*)d_ws;
    bf16* Ap = (bf16*)ws;
    bf16* Wt = (bf16*)(ws + AP_BYTES);
    bf16* tR = (bf16*)(ws + AP_BYTES + WT_BYTES);

    prologue_kernel<<<dim3(BB / 128, DIN / 128), 256, 0, stream>>>(x, cl, sL, sR, Ap, tR);
    transpose_kernel<<<dim3(DOUT / 256, DIN / 32), 256, 0, stream>>>(W, Wt);
    gemm_kernel<<<dim3((BB / 256) * (DOUT / 256)), 512, 0, stream>>>(Ap, Wt, tR, out);
}